// Round 4
// baseline (2262.802 us; speedup 1.0000x reference)
//
#include <hip/hip_runtime.h>
#include <math.h>

#define DEPTH_ 4
#define DIM_ 1024
#define HEADS_ 16
#define DHEAD_ 64
#define MLP_ 4096
#define CTX_ 1024
#define INNER_ 1024
#define B_ 4
#define N_ 1024
#define M_ 2048

typedef unsigned short u16;
typedef __attribute__((ext_vector_type(4))) unsigned short u16x4;
typedef __attribute__((ext_vector_type(8))) short bf16x8;
typedef __attribute__((ext_vector_type(4))) float f32x4;
typedef __attribute__((ext_vector_type(4))) int i32x4;

__device__ __forceinline__ u16 f2bf(float f) {
    unsigned u = __float_as_uint(f);
    return (u16)((u + 0x7fffu + ((u >> 16) & 1u)) >> 16);
}

#define GLOAD16(gp, sp)                                                        \
    __builtin_amdgcn_global_load_lds(                                          \
        (const __attribute__((address_space(1))) void*)(gp),                   \
        (__attribute__((address_space(3))) void*)(sp), 16, 0, 0)

// ---------------------------------------------------------------------------
// LayerNorm fp32 -> bf16 out. One block per row, 256 threads x float4.
// ---------------------------------------------------------------------------
__global__ __launch_bounds__(256) void ln_kernel(
    const float* __restrict__ x, const float* __restrict__ g,
    const float* __restrict__ b, u16* __restrict__ y) {
    int row = blockIdx.x;
    float4 v = ((const float4*)(x + (size_t)row * DIM_))[threadIdx.x];
    float s  = v.x + v.y + v.z + v.w;
    float ss = v.x * v.x + v.y * v.y + v.z * v.z + v.w * v.w;
    #pragma unroll
    for (int off = 32; off; off >>= 1) {
        s  += __shfl_down(s, off);
        ss += __shfl_down(ss, off);
    }
    __shared__ float red[10];
    int wid = threadIdx.x >> 6, lane = threadIdx.x & 63;
    if (lane == 0) { red[wid] = s; red[4 + wid] = ss; }
    __syncthreads();
    if (threadIdx.x == 0) {
        float ts  = red[0] + red[1] + red[2] + red[3];
        float tss = red[4] + red[5] + red[6] + red[7];
        float mu  = ts * (1.0f / DIM_);
        float var = tss * (1.0f / DIM_) - mu * mu;
        red[8] = mu;
        red[9] = rsqrtf(var + 1e-5f);
    }
    __syncthreads();
    float mu = red[8], rs = red[9];
    float4 gg = ((const float4*)g)[threadIdx.x];
    float4 bb = ((const float4*)b)[threadIdx.x];
    u16x4 o;
    o[0] = f2bf((v.x - mu) * rs * gg.x + bb.x);
    o[1] = f2bf((v.y - mu) * rs * gg.y + bb.y);
    o[2] = f2bf((v.z - mu) * rs * gg.z + bb.z);
    o[3] = f2bf((v.w - mu) * rs * gg.w + bb.w);
    ((u16x4*)(y + (size_t)row * DIM_))[threadIdx.x] = o;
}

// ---------------------------------------------------------------------------
// fp32 -> bf16 cast (context), float4 per thread
// ---------------------------------------------------------------------------
__global__ __launch_bounds__(256) void cast_kernel(const float* __restrict__ in,
                                                   u16* __restrict__ out) {
    int i = blockIdx.x * 256 + threadIdx.x;
    float4 v = ((const float4*)in)[i];
    u16x4 o = {f2bf(v.x), f2bf(v.y), f2bf(v.z), f2bf(v.w)};
    ((u16x4*)out)[i] = o;
}

// ---------------------------------------------------------------------------
// Weight transpose + cast: W[K][N] fp32 -> Wt[N][K] bf16. 32x32 tiles.
// ---------------------------------------------------------------------------
__global__ __launch_bounds__(256) void transpose_cast(
    const float* __restrict__ W, u16* __restrict__ Wt, int Kdim, int Ndim) {
    __shared__ float tile[32][33];
    int bx = blockIdx.x * 32;  // n
    int by = blockIdx.y * 32;  // k
    int t = threadIdx.x;
    int kl = t >> 3, n4 = (t & 7) * 4;
    float4 v = *(const float4*)(W + (size_t)(by + kl) * Ndim + bx + n4);
    tile[kl][n4 + 0] = v.x; tile[kl][n4 + 1] = v.y;
    tile[kl][n4 + 2] = v.z; tile[kl][n4 + 3] = v.w;
    __syncthreads();
    int nl = t >> 3, k4 = (t & 7) * 4;
    u16x4 o;
    #pragma unroll
    for (int j = 0; j < 4; ++j) o[j] = f2bf(tile[k4 + j][nl]);
    *(u16x4*)(Wt + (size_t)(bx + nl) * Kdim + by + k4) = o;
}

// ---------------------------------------------------------------------------
// MFMA GEMM, 2-phase double-buffered (T3 minimum recipe):
//   prologue STAGE(tile0); loop { STAGE(next); compute(cur); barrier; }
// C[M,N] = A[M,K] * Bt[N,K]^T, bf16 in, fp32 acc. 128x128 tile, BK=32,
// 4 waves (2x2), 16 mfma/K-step. SPLITK>1: blockIdx.z owns a K-chunk,
// partials combined via fp32 atomicAdd (EPI=2 only).
// EPI: 0 = bf16 out; 1 = +bias+gelu bf16; 2 = fp32 residual += acc+bias;
//      4 = bf16 out + V-part (col>=2048) -> vt (QKV gemm, rpb=1024)
//      5 = bf16 out + V-part (col>=1024) -> vt (KV  gemm, rpb=2048)
// ---------------------------------------------------------------------------
template <int EPI, int SPLITK>
__global__ __launch_bounds__(256) void gemm_mfma(
    const u16* __restrict__ A, const u16* __restrict__ Bt,
    const float* __restrict__ bias, void* __restrict__ Cout,
    u16* __restrict__ vt, int Mdim, int Ndim, int Kdim) {
    __shared__ __align__(16) u16 As[2][128 * 32];
    __shared__ __align__(16) u16 Bs[2][128 * 32];
    const int t = threadIdx.x;
    const int lane = t & 63, w = t >> 6;
    const int c = lane & 15, g = lane >> 4;
    const int wy = w >> 1, wx = w & 1;
    const int m0 = blockIdx.y * 128, n0 = blockIdx.x * 128;

    f32x4 acc[4][4] = {};

    const int srow = w * 32 + (lane >> 2);
    const int scb  = (lane & 3) * 8;
    const u16* Ag = A + (size_t)(m0 + srow) * Kdim + scb;
    const u16* Bg = Bt + (size_t)(n0 + srow) * Kdim + scb;

    auto stage = [&](int buf, int k0) {
        GLOAD16(Ag + k0, &As[buf][w * 1024]);
        GLOAD16(Ag + k0 + (size_t)16 * Kdim, &As[buf][w * 1024 + 512]);
        GLOAD16(Bg + k0, &Bs[buf][w * 1024]);
        GLOAD16(Bg + k0 + (size_t)16 * Kdim, &Bs[buf][w * 1024 + 512]);
    };
    auto compute = [&](int buf) {
        bf16x8 a[4], b[4];
        #pragma unroll
        for (int i = 0; i < 4; ++i)
            a[i] = *(const bf16x8*)&As[buf][(wy * 64 + i * 16 + c) * 32 + g * 8];
        #pragma unroll
        for (int i = 0; i < 4; ++i)
            b[i] = *(const bf16x8*)&Bs[buf][(wx * 64 + i * 16 + c) * 32 + g * 8];
        #pragma unroll
        for (int i = 0; i < 4; ++i)
            #pragma unroll
            for (int j = 0; j < 4; ++j)
                acc[i][j] = __builtin_amdgcn_mfma_f32_16x16x32_bf16(
                    a[i], b[j], acc[i][j], 0, 0, 0);
    };

    const int kchunk = Kdim / SPLITK;
    const int kbeg = blockIdx.z * kchunk;
    const int nsteps = kchunk / 32;

    stage(0, kbeg);
    __syncthreads();
    int cur = 0;
    for (int s = 0; s < nsteps; ++s) {
        if (s + 1 < nsteps) stage(cur ^ 1, kbeg + (s + 1) * 32);
        compute(cur);
        __syncthreads();
        cur ^= 1;
    }

    constexpr int VTHRESH = (EPI == 4) ? 2048 : 1024;
    constexpr int RPB     = (EPI == 4) ? 1024 : 2048;
    constexpr int KVL     = (EPI == 4) ? 1024 : 2048;

    #pragma unroll
    for (int i = 0; i < 4; ++i) {
        int row0 = m0 + wy * 64 + i * 16 + g * 4;
        #pragma unroll
        for (int j = 0; j < 4; ++j) {
            int col = n0 + wx * 64 + j * 16 + c;
            u16x4 o4;
            #pragma unroll
            for (int r = 0; r < 4; ++r) {
                float v = acc[i][j][r];
                size_t idx = (size_t)(row0 + r) * Ndim + col;
                if constexpr (EPI == 0 || EPI == 4 || EPI == 5) {
                    u16 bv = f2bf(v);
                    ((u16*)Cout)[idx] = bv;
                    o4[r] = bv;
                } else if constexpr (EPI == 1) {
                    v += bias[col];
                    v = 0.5f * v * (1.0f + erff(v * 0.70710678118654752f));
                    ((u16*)Cout)[idx] = f2bf(v);
                } else {
                    float* Cf = (float*)Cout;
                    float add = v + ((SPLITK == 1 || blockIdx.z == 0)
                                         ? bias[col] : 0.f);
                    if constexpr (SPLITK > 1)
                        atomicAdd(&Cf[idx], add);
                    else
                        Cf[idx] += add;
                }
            }
            if constexpr (EPI == 4 || EPI == 5) {
                if (n0 + wx * 64 + j * 16 >= VTHRESH) {
                    int hh = (col - VTHRESH) >> 6;
                    int dd = col & 63;
                    int bi = row0 / RPB;
                    int kv = row0 % RPB;
                    *(u16x4*)&vt[(((size_t)bi * HEADS_ + hh) * 64 + dd) * KVL +
                                 kv] = o4;
                }
            }
        }
    }
}

// ---------------------------------------------------------------------------
// MFMA flash attention v3 (2-phase double-buffered K/V staging).
// Block = 4 waves, 64 q-rows (16/wave), one (b,h). KVBLK=64.
// Swapped QK^T (mfma(K,Q)); in-register softmax; P redistributed via shfl.
// K and V^T staged via global_load_lds with pre-swizzled global source.
// ---------------------------------------------------------------------------
template <int KLEN, int IS_SA>
__global__ __launch_bounds__(256) void attn_mfma2(
    const u16* __restrict__ Qsrc, const u16* __restrict__ Ksrc,
    const u16* __restrict__ Vtg, const int* __restrict__ mask,
    u16* __restrict__ O) {
    constexpr int QSTR = IS_SA ? 3 * INNER_ : INNER_;
    constexpr int KSTR = IS_SA ? 3 * INNER_ : 2 * INNER_;
    constexpr int KOFF = IS_SA ? INNER_ : 0;

    __shared__ __align__(16) u16 Ks[2][64 * 64];
    __shared__ __align__(16) u16 Vs[2][64 * 64];

    const int t = threadIdx.x;
    const int lane = t & 63, w = t >> 6;
    const int c = lane & 15, g = lane >> 4;
    const int h = blockIdx.y, bb = blockIdx.z;
    const int q0 = blockIdx.x * 64;
    const int kvbase = bb * KLEN;

    const u16* qp =
        Qsrc + (size_t)(bb * N_ + q0 + w * 16 + c) * QSTR + h * 64 + g * 8;
    bf16x8 qf[2];
    qf[0] = *(const bf16x8*)qp;
    qf[1] = *(const bf16x8*)(qp + 32);

    const int sl_r = lane >> 3;
    const int scol = ((lane & 7) ^ sl_r) * 8;  // swizzled source col (u16)
    const int r0 = w * 16, r1 = w * 16 + 8;
    const u16* Kg0 = Ksrc + (size_t)(kvbase + r0 + sl_r) * KSTR + KOFF +
                     h * 64 + scol;
    const u16* Kg1 = Ksrc + (size_t)(kvbase + r1 + sl_r) * KSTR + KOFF +
                     h * 64 + scol;
    const u16* Vg0 =
        Vtg + ((size_t)(bb * HEADS_ + h) * 64 + r0 + sl_r) * KLEN + scol;
    const u16* Vg1 =
        Vtg + ((size_t)(bb * HEADS_ + h) * 64 + r1 + sl_r) * KLEN + scol;

    auto stageKV = [&](int buf, int kt) {
        GLOAD16(Kg0 + (size_t)kt * 64 * KSTR, &Ks[buf][r0 * 64]);
        GLOAD16(Kg1 + (size_t)kt * 64 * KSTR, &Ks[buf][r1 * 64]);
        GLOAD16(Vg0 + kt * 64, &Vs[buf][r0 * 64]);
        GLOAD16(Vg1 + kt * 64, &Vs[buf][r1 * 64]);
    };

    f32x4 o[4] = {};
    float mr = -1e30f, lr = 0.f;
    const int srcA = c + 32 * (g & 1);
    const int srcB = srcA + 16;
    const bool hi = (g & 2) != 0;
    constexpr int NT = KLEN / 64;

    stageKV(0, 0);
    __syncthreads();
    int cur = 0;

    for (int kt = 0; kt < NT; ++kt) {
        if (kt + 1 < NT) stageKV(cur ^ 1, kt + 1);
        float negm_reg = 0.f;
        if constexpr (IS_SA)
            negm_reg = 1e11f * (float)(1 - mask[bb * N_ + kt * 64 + lane]);

        // S^T = K Q^T : sv[kvb] holds S[q = c][kv = kvb*16 + g*4 + r]
        f32x4 sv[4] = {};
        #pragma unroll
        for (int kvb = 0; kvb < 4; ++kvb) {
            #pragma unroll
            for (int f = 0; f < 2; ++f) {
                bf16x8 kf = *(const bf16x8*)&Ks[cur][(kvb * 16 + c) * 64 +
                                                     (((g + 4 * f) ^ (c & 7)) * 8)];
                sv[kvb] = __builtin_amdgcn_mfma_f32_16x16x32_bf16(
                    kf, qf[f], sv[kvb], 0, 0, 0);
            }
        }
        #pragma unroll
        for (int kvb = 0; kvb < 4; ++kvb)
            #pragma unroll
            for (int r = 0; r < 4; ++r) {
                float s = sv[kvb][r] * 0.125f;
                if constexpr (IS_SA)
                    s -= __shfl(negm_reg, kvb * 16 + g * 4 + r);
                sv[kvb][r] = s;
            }

        float tm = sv[0][0];
        #pragma unroll
        for (int kvb = 0; kvb < 4; ++kvb)
            #pragma unroll
            for (int r = 0; r < 4; ++r) tm = fmaxf(tm, sv[kvb][r]);
        tm = fmaxf(tm, __shfl_xor(tm, 16));
        tm = fmaxf(tm, __shfl_xor(tm, 32));
        float mnew = fmaxf(mr, tm);
        float corr = __expf(mr - mnew);
        mr = mnew;

        float ps = 0.f;
        #pragma unroll
        for (int kvb = 0; kvb < 4; ++kvb)
            #pragma unroll
            for (int r = 0; r < 4; ++r) {
                float p = __expf(sv[kvb][r] - mr);
                sv[kvb][r] = p;
                ps += p;
            }
        ps += __shfl_xor(ps, 16);
        ps += __shfl_xor(ps, 32);
        lr = lr * corr + ps;

        float corrO[4];
        #pragma unroll
        for (int r = 0; r < 4; ++r) corrO[r] = __shfl(corr, g * 4 + r);
        #pragma unroll
        for (int db = 0; db < 4; ++db)
            #pragma unroll
            for (int r = 0; r < 4; ++r) o[db][r] *= corrO[r];

        unsigned pk[4][2];
        #pragma unroll
        for (int kvb = 0; kvb < 4; ++kvb)
            #pragma unroll
            for (int j = 0; j < 2; ++j)
                pk[kvb][j] = ((unsigned)f2bf(sv[kvb][2 * j + 1]) << 16) |
                             (unsigned)f2bf(sv[kvb][2 * j]);

        #pragma unroll
        for (int pv = 0; pv < 2; ++pv) {
            int a0 = __shfl((int)pk[2 * pv][0], srcA);
            int b0 = __shfl((int)pk[2 * pv + 1][0], srcA);
            int a1 = __shfl((int)pk[2 * pv][1], srcA);
            int b1 = __shfl((int)pk[2 * pv + 1][1], srcA);
            int a2 = __shfl((int)pk[2 * pv][0], srcB);
            int b2 = __shfl((int)pk[2 * pv + 1][0], srcB);
            int a3 = __shfl((int)pk[2 * pv][1], srcB);
            int b3 = __shfl((int)pk[2 * pv + 1][1], srcB);
            i32x4 tw = {hi ? b0 : a0, hi ? b1 : a1, hi ? b2 : a2,
                        hi ? b3 : a3};
            bf16x8 pa = *(bf16x8*)&tw;
            #pragma unroll
            for (int db = 0; db < 4; ++db) {
                bf16x8 vf = *(const bf16x8*)&Vs[cur][(db * 16 + c) * 64 +
                                                     (((g + 4 * pv) ^ (c & 7)) * 8)];
                o[db] = __builtin_amdgcn_mfma_f32_16x16x32_bf16(pa, vf, o[db],
                                                                0, 0, 0);
            }
        }
        __syncthreads();
        cur ^= 1;
    }

    float inv = 1.f / lr;
    float invO[4];
    #pragma unroll
    for (int r = 0; r < 4; ++r) invO[r] = __shfl(inv, g * 4 + r);
    #pragma unroll
    for (int db = 0; db < 4; ++db)
        #pragma unroll
        for (int r = 0; r < 4; ++r) {
            size_t idx =
                (size_t)(bb * N_ + q0 + w * 16 + g * 4 + r) * INNER_ +
                h * 64 + db * 16 + c;
            O[idx] = f2bf(o[db][r] * invO[r]);
        }
}

// ---------------------------------------------------------------------------
extern "C" void kernel_launch(void* const* d_in, const int* in_sizes, int n_in,
                              void* d_out, int out_size, void* d_ws,
                              size_t ws_size, hipStream_t stream) {
    const float* x     = (const float*)d_in[0];
    const float* ctx   = (const float*)d_in[1];
    const int*   mask  = (const int*)d_in[2];
    const float* ln_g  = (const float*)d_in[3];
    const float* ln_b  = (const float*)d_in[4];
    const float* Wqkv  = (const float*)d_in[5];
    const float* Wo_sa = (const float*)d_in[6];
    const float* bo_sa = (const float*)d_in[7];
    const float* Wkv   = (const float*)d_in[8];
    const float* Wq    = (const float*)d_in[9];
    const float* Wo_ca = (const float*)d_in[10];
    const float* bo_ca = (const float*)d_in[11];
    const float* W1    = (const float*)d_in[12];
    const float* b1    = (const float*)d_in[13];
    const float* W2    = (const float*)d_in[14];
    const float* b2    = (const float*)d_in[15];
    float* xout = (float*)d_out;

    char* ws = (char*)d_ws;
    u16* lnout = (u16*)ws;                        // 8MB (also attn out)
    u16* big   = (u16*)(ws + (8ull << 20));       // 32MB: qkv / kv / h1
    u16* qca   = (u16*)(ws + (40ull << 20));      // 8MB
    u16* ctxb  = (u16*)(ws + (48ull << 20));      // 16MB
    u16* wt    = (u16*)(ws + (64ull << 20));      // 8MB: transposed weight
    u16* vt_sa = (u16*)(ws + (72ull << 20));      // 8MB: V^T self-attn
    u16* vt_ca = (u16*)(ws + (80ull << 20));      // 16MB: V^T cross-attn
    u16* aout  = lnout;

    hipMemcpyAsync(xout, x, sizeof(float) * B_ * N_ * DIM_,
                   hipMemcpyDeviceToDevice, stream);
    cast_kernel<<<B_ * M_ * CTX_ / 1024, 256, 0, stream>>>(ctx, ctxb);

    const int ROWS = B_ * N_;    // 4096
    const int CROWS = B_ * M_;   // 8192
    dim3 blk(256);

    for (int i = 0; i < DEPTH_; ++i) {
        const float* g  = ln_g + (size_t)(i * 3) * DIM_;
        const float* bb = ln_b + (size_t)(i * 3) * DIM_;

        // ---- self-attention ----
        ln_kernel<<<ROWS, blk, 0, stream>>>(xout, g, bb, lnout);
        transpose_cast<<<dim3(3 * INNER_ / 32, DIM_ / 32), blk, 0, stream>>>(
            Wqkv + (size_t)i * DIM_ * 3 * INNER_, wt, DIM_, 3 * INNER_);
        gemm_mfma<4, 1><<<dim3(3 * INNER_ / 128, ROWS / 128, 1), blk, 0,
                          stream>>>(lnout, wt, nullptr, big, vt_sa, ROWS,
                                    3 * INNER_, DIM_);
        attn_mfma2<N_, 1><<<dim3(N_ / 64, HEADS_, B_), blk, 0, stream>>>(
            big, big, vt_sa, mask, aout);
        transpose_cast<<<dim3(DIM_ / 32, INNER_ / 32), blk, 0, stream>>>(
            Wo_sa + (size_t)i * INNER_ * DIM_, wt, INNER_, DIM_);
        gemm_mfma<2, 2><<<dim3(DIM_ / 128, ROWS / 128, 2), blk, 0, stream>>>(
            aout, wt, bo_sa + (size_t)i * DIM_, xout, nullptr, ROWS, DIM_,
            INNER_);

        // ---- cross-attention ----
        ln_kernel<<<ROWS, blk, 0, stream>>>(xout, g + DIM_, bb + DIM_, lnout);
        transpose_cast<<<dim3(INNER_ / 32, DIM_ / 32), blk, 0, stream>>>(
            Wq + (size_t)i * DIM_ * INNER_, wt, DIM_, INNER_);
        gemm_mfma<0, 1><<<dim3(INNER_ / 128, ROWS / 128, 1), blk, 0, stream>>>(
            lnout, wt, nullptr, qca, nullptr, ROWS, INNER_, DIM_);
        transpose_cast<<<dim3(2 * INNER_ / 32, CTX_ / 32), blk, 0, stream>>>(
            Wkv + (size_t)i * CTX_ * 2 * INNER_, wt, CTX_, 2 * INNER_);
        gemm_mfma<5, 1><<<dim3(2 * INNER_ / 128, CROWS / 128, 1), blk, 0,
                          stream>>>(ctxb, wt, nullptr, big, vt_ca, CROWS,
                                    2 * INNER_, CTX_);
        attn_mfma2<M_, 0><<<dim3(N_ / 64, HEADS_, B_), blk, 0, stream>>>(
            qca, big, vt_ca, mask, aout);
        transpose_cast<<<dim3(DIM_ / 32, INNER_ / 32), blk, 0, stream>>>(
            Wo_ca + (size_t)i * INNER_ * DIM_, wt, INNER_, DIM_);
        gemm_mfma<2, 2><<<dim3(DIM_ / 128, ROWS / 128, 2), blk, 0, stream>>>(
            aout, wt, bo_ca + (size_t)i * DIM_, xout, nullptr, ROWS, DIM_,
            INNER_);

        // ---- feed-forward ----
        ln_kernel<<<ROWS, blk, 0, stream>>>(xout, g + 2 * DIM_, bb + 2 * DIM_,
                                            lnout);
        transpose_cast<<<dim3(MLP_ / 32, DIM_ / 32), blk, 0, stream>>>(
            W1 + (size_t)i * DIM_ * MLP_, wt, DIM_, MLP_);
        gemm_mfma<1, 1><<<dim3(MLP_ / 128, ROWS / 128, 1), blk, 0, stream>>>(
            lnout, wt, b1 + (size_t)i * MLP_, big, nullptr, ROWS, MLP_, DIM_);
        transpose_cast<<<dim3(DIM_ / 32, MLP_ / 32), blk, 0, stream>>>(
            W2 + (size_t)i * MLP_ * DIM_, wt, MLP_, DIM_);
        gemm_mfma<2, 4><<<dim3(DIM_ / 128, ROWS / 128, 4), blk, 0, stream>>>(
            big, wt, b2 + (size_t)i * DIM_, xout, nullptr, ROWS, DIM_, MLP_);
    }
}

// Round 5
// 2217.825 us; speedup vs baseline: 1.0203x; 1.0203x over previous
//
#include <hip/hip_runtime.h>
#include <math.h>

#define DEPTH_ 4
#define DIM_ 1024
#define HEADS_ 16
#define DHEAD_ 64
#define MLP_ 4096
#define CTX_ 1024
#define INNER_ 1024
#define B_ 4
#define N_ 1024
#define M_ 2048

typedef unsigned short u16;
typedef __attribute__((ext_vector_type(4))) unsigned short u16x4;
typedef __attribute__((ext_vector_type(8))) short bf16x8;
typedef __attribute__((ext_vector_type(4))) float f32x4;
typedef __attribute__((ext_vector_type(4))) int i32x4;

__device__ __forceinline__ u16 f2bf(float f) {
    unsigned u = __float_as_uint(f);
    return (u16)((u + 0x7fffu + ((u >> 16) & 1u)) >> 16);
}

#define GLOAD16(gp, sp)                                                        \
    __builtin_amdgcn_global_load_lds(                                          \
        (const __attribute__((address_space(1))) void*)(gp),                   \
        (__attribute__((address_space(3))) void*)(sp), 16, 0, 0)

// ---------------------------------------------------------------------------
// LayerNorm fp32 -> bf16 out. One block per row, 256 threads x float4.
// ---------------------------------------------------------------------------
__global__ __launch_bounds__(256) void ln_kernel(
    const float* __restrict__ x, const float* __restrict__ g,
    const float* __restrict__ b, u16* __restrict__ y) {
    int row = blockIdx.x;
    float4 v = ((const float4*)(x + (size_t)row * DIM_))[threadIdx.x];
    float s  = v.x + v.y + v.z + v.w;
    float ss = v.x * v.x + v.y * v.y + v.z * v.z + v.w * v.w;
    #pragma unroll
    for (int off = 32; off; off >>= 1) {
        s  += __shfl_down(s, off);
        ss += __shfl_down(ss, off);
    }
    __shared__ float red[10];
    int wid = threadIdx.x >> 6, lane = threadIdx.x & 63;
    if (lane == 0) { red[wid] = s; red[4 + wid] = ss; }
    __syncthreads();
    if (threadIdx.x == 0) {
        float ts  = red[0] + red[1] + red[2] + red[3];
        float tss = red[4] + red[5] + red[6] + red[7];
        float mu  = ts * (1.0f / DIM_);
        float var = tss * (1.0f / DIM_) - mu * mu;
        red[8] = mu;
        red[9] = rsqrtf(var + 1e-5f);
    }
    __syncthreads();
    float mu = red[8], rs = red[9];
    float4 gg = ((const float4*)g)[threadIdx.x];
    float4 bb = ((const float4*)b)[threadIdx.x];
    u16x4 o;
    o[0] = f2bf((v.x - mu) * rs * gg.x + bb.x);
    o[1] = f2bf((v.y - mu) * rs * gg.y + bb.y);
    o[2] = f2bf((v.z - mu) * rs * gg.z + bb.z);
    o[3] = f2bf((v.w - mu) * rs * gg.w + bb.w);
    ((u16x4*)(y + (size_t)row * DIM_))[threadIdx.x] = o;
}

// ---------------------------------------------------------------------------
// fp32 -> bf16 cast (context), float4 per thread
// ---------------------------------------------------------------------------
__global__ __launch_bounds__(256) void cast_kernel(const float* __restrict__ in,
                                                   u16* __restrict__ out) {
    int i = blockIdx.x * 256 + threadIdx.x;
    float4 v = ((const float4*)in)[i];
    u16x4 o = {f2bf(v.x), f2bf(v.y), f2bf(v.z), f2bf(v.w)};
    ((u16x4*)out)[i] = o;
}

// ---------------------------------------------------------------------------
// Weight transpose + cast: W[K][N] fp32 -> Wt[N][K] bf16. 32x32 tiles.
// ---------------------------------------------------------------------------
__global__ __launch_bounds__(256) void transpose_cast(
    const float* __restrict__ W, u16* __restrict__ Wt, int Kdim, int Ndim) {
    __shared__ float tile[32][33];
    int bx = blockIdx.x * 32;  // n
    int by = blockIdx.y * 32;  // k
    int t = threadIdx.x;
    int kl = t >> 3, n4 = (t & 7) * 4;
    float4 v = *(const float4*)(W + (size_t)(by + kl) * Ndim + bx + n4);
    tile[kl][n4 + 0] = v.x; tile[kl][n4 + 1] = v.y;
    tile[kl][n4 + 2] = v.z; tile[kl][n4 + 3] = v.w;
    __syncthreads();
    int nl = t >> 3, k4 = (t & 7) * 4;
    u16x4 o;
    #pragma unroll
    for (int j = 0; j < 4; ++j) o[j] = f2bf(tile[k4 + j][nl]);
    *(u16x4*)(Wt + (size_t)(bx + nl) * Kdim + by + k4) = o;
}

// ---------------------------------------------------------------------------
// MFMA GEMM, depth-2 prefetch pipeline (T3+T4): 4 LDS buffers, counted
// vmcnt (never 0 in main loop), ONE raw s_barrier per K-step.
//   iter s: stage(s+2) ; vmcnt(8) [tile s landed, s+1/s+2 in flight] ;
//           s_barrier ; compute(s)
// LDS fragment reads XOR-swizzled (T2) via pre-swizzled global source.
// C[M,N] = A[M,K] * Bt[N,K]^T, bf16 in, fp32 acc. 128x128 tile, BK=32,
// 4 waves (2x2), 16 mfma/K-step. SPLITK>1: blockIdx.z owns a K-chunk,
// partials combined via fp32 atomicAdd (EPI=2 only).
// EPI: 0 = bf16 out; 1 = +bias+gelu bf16; 2 = fp32 residual += acc+bias;
//      4 = bf16 out + V-part (col>=2048) -> vt (QKV gemm, rpb=1024)
//      5 = bf16 out + V-part (col>=1024) -> vt (KV  gemm, rpb=2048)
// ---------------------------------------------------------------------------
template <int EPI, int SPLITK>
__global__ __launch_bounds__(256) void gemm_mfma(
    const u16* __restrict__ A, const u16* __restrict__ Bt,
    const float* __restrict__ bias, void* __restrict__ Cout,
    u16* __restrict__ vt, int Mdim, int Ndim, int Kdim) {
    __shared__ __align__(16) u16 As[4][128 * 32];
    __shared__ __align__(16) u16 Bs[4][128 * 32];
    const int t = threadIdx.x;
    const int lane = t & 63, w = t >> 6;
    const int c = lane & 15, g = lane >> 4;
    const int wy = w >> 1, wx = w & 1;
    const int m0 = blockIdx.y * 128, n0 = blockIdx.x * 128;

    f32x4 acc[4][4] = {};

    // staging: lane covers row srow=(w*32+(lane>>2)), 16B-block (lane&3),
    // source block pre-swizzled by (row>>1)&3 so LDS slot b holds global
    // block b ^ ((row>>1)&3)  (both halves: +16 rows keeps (row>>1)&3).
    const int srow = w * 32 + (lane >> 2);
    const int scb  = (((lane & 3) ^ ((srow >> 1) & 3)) * 8);
    const u16* Ag = A + (size_t)(m0 + srow) * Kdim + scb;
    const u16* Bg = Bt + (size_t)(n0 + srow) * Kdim + scb;

    auto stage = [&](int buf, int k0) {
        GLOAD16(Ag + k0, &As[buf][w * 1024]);
        GLOAD16(Ag + k0 + (size_t)16 * Kdim, &As[buf][w * 1024 + 512]);
        GLOAD16(Bg + k0, &Bs[buf][w * 1024]);
        GLOAD16(Bg + k0 + (size_t)16 * Kdim, &Bs[buf][w * 1024 + 512]);
    };
    // read swizzle: row = wy*64+i*16+c -> (row>>1)&3 == (c>>1)&3
    const int rsw = (c >> 1) & 3;
    auto compute = [&](int buf) {
        bf16x8 a[4], b[4];
        #pragma unroll
        for (int i = 0; i < 4; ++i)
            a[i] = *(const bf16x8*)&As[buf][(wy * 64 + i * 16 + c) * 32 +
                                            ((g ^ rsw) * 8)];
        #pragma unroll
        for (int i = 0; i < 4; ++i)
            b[i] = *(const bf16x8*)&Bs[buf][(wx * 64 + i * 16 + c) * 32 +
                                            ((g ^ rsw) * 8)];
        __builtin_amdgcn_s_setprio(1);
        #pragma unroll
        for (int i = 0; i < 4; ++i)
            #pragma unroll
            for (int j = 0; j < 4; ++j)
                acc[i][j] = __builtin_amdgcn_mfma_f32_16x16x32_bf16(
                    a[i], b[j], acc[i][j], 0, 0, 0);
        __builtin_amdgcn_s_setprio(0);
    };

    const int kchunk = Kdim / SPLITK;
    const int kbeg = blockIdx.z * kchunk;
    const int nsteps = kchunk / 32;  // >= 16 for all our shapes

    stage(0, kbeg);
    stage(1, kbeg + 32);
    int s = 0;
    for (; s + 2 < nsteps; ++s) {
        stage((s + 2) & 3, kbeg + (s + 2) * 32);
        asm volatile("s_waitcnt vmcnt(8)" ::: "memory");
        __builtin_amdgcn_s_barrier();
        compute(s & 3);
    }
    asm volatile("s_waitcnt vmcnt(4)" ::: "memory");
    __builtin_amdgcn_s_barrier();
    compute(s & 3);
    ++s;
    asm volatile("s_waitcnt vmcnt(0)" ::: "memory");
    __builtin_amdgcn_s_barrier();
    compute(s & 3);

    constexpr int VTHRESH = (EPI == 4) ? 2048 : 1024;
    constexpr int RPB     = (EPI == 4) ? 1024 : 2048;
    constexpr int KVL     = (EPI == 4) ? 1024 : 2048;

    #pragma unroll
    for (int i = 0; i < 4; ++i) {
        int row0 = m0 + wy * 64 + i * 16 + g * 4;
        #pragma unroll
        for (int j = 0; j < 4; ++j) {
            int col = n0 + wx * 64 + j * 16 + c;
            u16x4 o4;
            #pragma unroll
            for (int r = 0; r < 4; ++r) {
                float v = acc[i][j][r];
                size_t idx = (size_t)(row0 + r) * Ndim + col;
                if constexpr (EPI == 0 || EPI == 4 || EPI == 5) {
                    u16 bv = f2bf(v);
                    ((u16*)Cout)[idx] = bv;
                    o4[r] = bv;
                } else if constexpr (EPI == 1) {
                    v += bias[col];
                    v = 0.5f * v * (1.0f + erff(v * 0.70710678118654752f));
                    ((u16*)Cout)[idx] = f2bf(v);
                } else {
                    float* Cf = (float*)Cout;
                    float add = v + ((SPLITK == 1 || blockIdx.z == 0)
                                         ? bias[col] : 0.f);
                    if constexpr (SPLITK > 1)
                        atomicAdd(&Cf[idx], add);
                    else
                        Cf[idx] += add;
                }
            }
            if constexpr (EPI == 4 || EPI == 5) {
                if (n0 + wx * 64 + j * 16 >= VTHRESH) {
                    int hh = (col - VTHRESH) >> 6;
                    int dd = col & 63;
                    int bi = row0 / RPB;
                    int kv = row0 % RPB;
                    *(u16x4*)&vt[(((size_t)bi * HEADS_ + hh) * 64 + dd) * KVL +
                                 kv] = o4;
                }
            }
        }
    }
}

// ---------------------------------------------------------------------------
// MFMA flash attention (2-phase double-buffered K/V staging).
// Block = 4 waves, 64 q-rows (16/wave), one (b,h). KVBLK=64.
// Swapped QK^T (mfma(K,Q)); in-register softmax; P redistributed via shfl.
// K and V^T staged via global_load_lds with pre-swizzled global source.
// ---------------------------------------------------------------------------
template <int KLEN, int IS_SA>
__global__ __launch_bounds__(256) void attn_mfma2(
    const u16* __restrict__ Qsrc, const u16* __restrict__ Ksrc,
    const u16* __restrict__ Vtg, const int* __restrict__ mask,
    u16* __restrict__ O) {
    constexpr int QSTR = IS_SA ? 3 * INNER_ : INNER_;
    constexpr int KSTR = IS_SA ? 3 * INNER_ : 2 * INNER_;
    constexpr int KOFF = IS_SA ? INNER_ : 0;

    __shared__ __align__(16) u16 Ks[2][64 * 64];
    __shared__ __align__(16) u16 Vs[2][64 * 64];

    const int t = threadIdx.x;
    const int lane = t & 63, w = t >> 6;
    const int c = lane & 15, g = lane >> 4;
    const int h = blockIdx.y, bb = blockIdx.z;
    const int q0 = blockIdx.x * 64;
    const int kvbase = bb * KLEN;

    const u16* qp =
        Qsrc + (size_t)(bb * N_ + q0 + w * 16 + c) * QSTR + h * 64 + g * 8;
    bf16x8 qf[2];
    qf[0] = *(const bf16x8*)qp;
    qf[1] = *(const bf16x8*)(qp + 32);

    const int sl_r = lane >> 3;
    const int scol = ((lane & 7) ^ sl_r) * 8;  // swizzled source col (u16)
    const int r0 = w * 16, r1 = w * 16 + 8;
    const u16* Kg0 = Ksrc + (size_t)(kvbase + r0 + sl_r) * KSTR + KOFF +
                     h * 64 + scol;
    const u16* Kg1 = Ksrc + (size_t)(kvbase + r1 + sl_r) * KSTR + KOFF +
                     h * 64 + scol;
    const u16* Vg0 =
        Vtg + ((size_t)(bb * HEADS_ + h) * 64 + r0 + sl_r) * KLEN + scol;
    const u16* Vg1 =
        Vtg + ((size_t)(bb * HEADS_ + h) * 64 + r1 + sl_r) * KLEN + scol;

    auto stageKV = [&](int buf, int kt) {
        GLOAD16(Kg0 + (size_t)kt * 64 * KSTR, &Ks[buf][r0 * 64]);
        GLOAD16(Kg1 + (size_t)kt * 64 * KSTR, &Ks[buf][r1 * 64]);
        GLOAD16(Vg0 + kt * 64, &Vs[buf][r0 * 64]);
        GLOAD16(Vg1 + kt * 64, &Vs[buf][r1 * 64]);
    };

    f32x4 o[4] = {};
    float mr = -1e30f, lr = 0.f;
    const int srcA = c + 32 * (g & 1);
    const int srcB = srcA + 16;
    const bool hi = (g & 2) != 0;
    constexpr int NT = KLEN / 64;

    stageKV(0, 0);
    __syncthreads();
    int cur = 0;

    for (int kt = 0; kt < NT; ++kt) {
        if (kt + 1 < NT) stageKV(cur ^ 1, kt + 1);
        float negm_reg = 0.f;
        if constexpr (IS_SA)
            negm_reg = 1e11f * (float)(1 - mask[bb * N_ + kt * 64 + lane]);

        // S^T = K Q^T : sv[kvb] holds S[q = c][kv = kvb*16 + g*4 + r]
        f32x4 sv[4] = {};
        #pragma unroll
        for (int kvb = 0; kvb < 4; ++kvb) {
            #pragma unroll
            for (int f = 0; f < 2; ++f) {
                bf16x8 kf = *(const bf16x8*)&Ks[cur][(kvb * 16 + c) * 64 +
                                                     (((g + 4 * f) ^ (c & 7)) * 8)];
                sv[kvb] = __builtin_amdgcn_mfma_f32_16x16x32_bf16(
                    kf, qf[f], sv[kvb], 0, 0, 0);
            }
        }
        #pragma unroll
        for (int kvb = 0; kvb < 4; ++kvb)
            #pragma unroll
            for (int r = 0; r < 4; ++r) {
                float s = sv[kvb][r] * 0.125f;
                if constexpr (IS_SA)
                    s -= __shfl(negm_reg, kvb * 16 + g * 4 + r);
                sv[kvb][r] = s;
            }

        float tm = sv[0][0];
        #pragma unroll
        for (int kvb = 0; kvb < 4; ++kvb)
            #pragma unroll
            for (int r = 0; r < 4; ++r) tm = fmaxf(tm, sv[kvb][r]);
        tm = fmaxf(tm, __shfl_xor(tm, 16));
        tm = fmaxf(tm, __shfl_xor(tm, 32));
        float mnew = fmaxf(mr, tm);
        float corr = __expf(mr - mnew);
        mr = mnew;

        float ps = 0.f;
        #pragma unroll
        for (int kvb = 0; kvb < 4; ++kvb)
            #pragma unroll
            for (int r = 0; r < 4; ++r) {
                float p = __expf(sv[kvb][r] - mr);
                sv[kvb][r] = p;
                ps += p;
            }
        ps += __shfl_xor(ps, 16);
        ps += __shfl_xor(ps, 32);
        lr = lr * corr + ps;

        float corrO[4];
        #pragma unroll
        for (int r = 0; r < 4; ++r) corrO[r] = __shfl(corr, g * 4 + r);
        #pragma unroll
        for (int db = 0; db < 4; ++db)
            #pragma unroll
            for (int r = 0; r < 4; ++r) o[db][r] *= corrO[r];

        unsigned pk[4][2];
        #pragma unroll
        for (int kvb = 0; kvb < 4; ++kvb)
            #pragma unroll
            for (int j = 0; j < 2; ++j)
                pk[kvb][j] = ((unsigned)f2bf(sv[kvb][2 * j + 1]) << 16) |
                             (unsigned)f2bf(sv[kvb][2 * j]);

        #pragma unroll
        for (int pv = 0; pv < 2; ++pv) {
            int a0 = __shfl((int)pk[2 * pv][0], srcA);
            int b0 = __shfl((int)pk[2 * pv + 1][0], srcA);
            int a1 = __shfl((int)pk[2 * pv][1], srcA);
            int b1 = __shfl((int)pk[2 * pv + 1][1], srcA);
            int a2 = __shfl((int)pk[2 * pv][0], srcB);
            int b2 = __shfl((int)pk[2 * pv + 1][0], srcB);
            int a3 = __shfl((int)pk[2 * pv][1], srcB);
            int b3 = __shfl((int)pk[2 * pv + 1][1], srcB);
            i32x4 tw = {hi ? b0 : a0, hi ? b1 : a1, hi ? b2 : a2,
                        hi ? b3 : a3};
            bf16x8 pa = *(bf16x8*)&tw;
            #pragma unroll
            for (int db = 0; db < 4; ++db) {
                bf16x8 vf = *(const bf16x8*)&Vs[cur][(db * 16 + c) * 64 +
                                                     (((g + 4 * pv) ^ (c & 7)) * 8)];
                o[db] = __builtin_amdgcn_mfma_f32_16x16x32_bf16(pa, vf, o[db],
                                                                0, 0, 0);
            }
        }
        __syncthreads();
        cur ^= 1;
    }

    float inv = 1.f / lr;
    float invO[4];
    #pragma unroll
    for (int r = 0; r < 4; ++r) invO[r] = __shfl(inv, g * 4 + r);
    #pragma unroll
    for (int db = 0; db < 4; ++db)
        #pragma unroll
        for (int r = 0; r < 4; ++r) {
            size_t idx =
                (size_t)(bb * N_ + q0 + w * 16 + g * 4 + r) * INNER_ +
                h * 64 + db * 16 + c;
            O[idx] = f2bf(o[db][r] * invO[r]);
        }
}

// ---------------------------------------------------------------------------
extern "C" void kernel_launch(void* const* d_in, const int* in_sizes, int n_in,
                              void* d_out, int out_size, void* d_ws,
                              size_t ws_size, hipStream_t stream) {
    const float* x     = (const float*)d_in[0];
    const float* ctx   = (const float*)d_in[1];
    const int*   mask  = (const int*)d_in[2];
    const float* ln_g  = (const float*)d_in[3];
    const float* ln_b  = (const float*)d_in[4];
    const float* Wqkv  = (const float*)d_in[5];
    const float* Wo_sa = (const float*)d_in[6];
    const float* bo_sa = (const float*)d_in[7];
    const float* Wkv   = (const float*)d_in[8];
    const float* Wq    = (const float*)d_in[9];
    const float* Wo_ca = (const float*)d_in[10];
    const float* bo_ca = (const float*)d_in[11];
    const float* W1    = (const float*)d_in[12];
    const float* b1    = (const float*)d_in[13];
    const float* W2    = (const float*)d_in[14];
    const float* b2    = (const float*)d_in[15];
    float* xout = (float*)d_out;

    char* ws = (char*)d_ws;
    u16* lnout = (u16*)ws;                        // 8MB (also attn out)
    u16* big   = (u16*)(ws + (8ull << 20));       // 32MB: qkv / kv / h1
    u16* qca   = (u16*)(ws + (40ull << 20));      // 8MB
    u16* ctxb  = (u16*)(ws + (48ull << 20));      // 16MB
    u16* wt    = (u16*)(ws + (64ull << 20));      // 8MB: transposed weight
    u16* vt_sa = (u16*)(ws + (72ull << 20));      // 8MB: V^T self-attn
    u16* vt_ca = (u16*)(ws + (80ull << 20));      // 16MB: V^T cross-attn
    u16* aout  = lnout;

    hipMemcpyAsync(xout, x, sizeof(float) * B_ * N_ * DIM_,
                   hipMemcpyDeviceToDevice, stream);
    cast_kernel<<<B_ * M_ * CTX_ / 1024, 256, 0, stream>>>(ctx, ctxb);

    const int ROWS = B_ * N_;    // 4096
    const int CROWS = B_ * M_;   // 8192
    dim3 blk(256);

    for (int i = 0; i < DEPTH_; ++i) {
        const float* g  = ln_g + (size_t)(i * 3) * DIM_;
        const float* bb = ln_b + (size_t)(i * 3) * DIM_;

        // ---- self-attention ----
        ln_kernel<<<ROWS, blk, 0, stream>>>(xout, g, bb, lnout);
        transpose_cast<<<dim3(3 * INNER_ / 32, DIM_ / 32), blk, 0, stream>>>(
            Wqkv + (size_t)i * DIM_ * 3 * INNER_, wt, DIM_, 3 * INNER_);
        gemm_mfma<4, 1><<<dim3(3 * INNER_ / 128, ROWS / 128, 1), blk, 0,
                          stream>>>(lnout, wt, nullptr, big, vt_sa, ROWS,
                                    3 * INNER_, DIM_);
        attn_mfma2<N_, 1><<<dim3(N_ / 64, HEADS_, B_), blk, 0, stream>>>(
            big, big, vt_sa, mask, aout);
        transpose_cast<<<dim3(DIM_ / 32, INNER_ / 32), blk, 0, stream>>>(
            Wo_sa + (size_t)i * INNER_ * DIM_, wt, INNER_, DIM_);
        gemm_mfma<2, 2><<<dim3(DIM_ / 128, ROWS / 128, 2), blk, 0, stream>>>(
            aout, wt, bo_sa + (size_t)i * DIM_, xout, nullptr, ROWS, DIM_,
            INNER_);

        // ---- cross-attention ----
        ln_kernel<<<ROWS, blk, 0, stream>>>(xout, g + DIM_, bb + DIM_, lnout);
        transpose_cast<<<dim3(INNER_ / 32, DIM_ / 32), blk, 0, stream>>>(
            Wq + (size_t)i * DIM_ * INNER_, wt, DIM_, INNER_);
        gemm_mfma<0, 1><<<dim3(INNER_ / 128, ROWS / 128, 1), blk, 0, stream>>>(
            lnout, wt, nullptr, qca, nullptr, ROWS, INNER_, DIM_);
        transpose_cast<<<dim3(2 * INNER_ / 32, CTX_ / 32), blk, 0, stream>>>(
            Wkv + (size_t)i * CTX_ * 2 * INNER_, wt, CTX_, 2 * INNER_);
        gemm_mfma<5, 1><<<dim3(2 * INNER_ / 128, CROWS / 128, 1), blk, 0,
                          stream>>>(ctxb, wt, nullptr, big, vt_ca, CROWS,
                                    2 * INNER_, CTX_);
        attn_mfma2<M_, 0><<<dim3(N_ / 64, HEADS_, B_), blk, 0, stream>>>(
            qca, big, vt_ca, mask, aout);
        transpose_cast<<<dim3(DIM_ / 32, INNER_ / 32), blk, 0, stream>>>(
            Wo_ca + (size_t)i * INNER_ * DIM_, wt, INNER_, DIM_);
        gemm_mfma<2, 2><<<dim3(DIM_ / 128, ROWS / 128, 2), blk, 0, stream>>>(
            aout, wt, bo_ca + (size_t)i * DIM_, xout, nullptr, ROWS, DIM_,
            INNER_);

        // ---- feed-forward ----
        ln_kernel<<<ROWS, blk, 0, stream>>>(xout, g + 2 * DIM_, bb + 2 * DIM_,
                                            lnout);
        transpose_cast<<<dim3(MLP_ / 32, DIM_ / 32), blk, 0, stream>>>(
            W1 + (size_t)i * DIM_ * MLP_, wt, DIM_, MLP_);
        gemm_mfma<1, 1><<<dim3(MLP_ / 128, ROWS / 128, 1), blk, 0, stream>>>(
            lnout, wt, b1 + (size_t)i * MLP_, big, nullptr, ROWS, MLP_, DIM_);
        transpose_cast<<<dim3(DIM_ / 32, MLP_ / 32), blk, 0, stream>>>(
            W2 + (size_t)i * MLP_ * DIM_, wt, MLP_, DIM_);
        gemm_mfma<2, 2><<<dim3(DIM_ / 128, ROWS / 128, 2), blk, 0, stream>>>(
            big, wt, b2 + (size_t)i * DIM_, xout, nullptr, ROWS, DIM_, MLP_);
    }
}

// Round 6
// 2111.664 us; speedup vs baseline: 1.0716x; 1.0503x over previous
//
#include <hip/hip_runtime.h>
#include <math.h>

#define DEPTH_ 4
#define DIM_ 1024
#define HEADS_ 16
#define DHEAD_ 64
#define MLP_ 4096
#define CTX_ 1024
#define INNER_ 1024
#define B_ 4
#define N_ 1024
#define M_ 2048

typedef unsigned short u16;
typedef __attribute__((ext_vector_type(4))) unsigned short u16x4;
typedef __attribute__((ext_vector_type(8))) short bf16x8;
typedef __attribute__((ext_vector_type(4))) float f32x4;
typedef __attribute__((ext_vector_type(4))) int i32x4;

__device__ __forceinline__ u16 f2bf(float f) {
    unsigned u = __float_as_uint(f);
    return (u16)((u + 0x7fffu + ((u >> 16) & 1u)) >> 16);
}

#define GLOAD16(gp, sp)                                                        \
    __builtin_amdgcn_global_load_lds(                                          \
        (const __attribute__((address_space(1))) void*)(gp),                   \
        (__attribute__((address_space(3))) void*)(sp), 16, 0, 0)

// ---------------------------------------------------------------------------
// LayerNorm fp32 -> bf16 out. One block per row, 256 threads x float4.
// ---------------------------------------------------------------------------
__global__ __launch_bounds__(256) void ln_kernel(
    const float* __restrict__ x, const float* __restrict__ g,
    const float* __restrict__ b, u16* __restrict__ y) {
    int row = blockIdx.x;
    float4 v = ((const float4*)(x + (size_t)row * DIM_))[threadIdx.x];
    float s  = v.x + v.y + v.z + v.w;
    float ss = v.x * v.x + v.y * v.y + v.z * v.z + v.w * v.w;
    #pragma unroll
    for (int off = 32; off; off >>= 1) {
        s  += __shfl_down(s, off);
        ss += __shfl_down(ss, off);
    }
    __shared__ float red[10];
    int wid = threadIdx.x >> 6, lane = threadIdx.x & 63;
    if (lane == 0) { red[wid] = s; red[4 + wid] = ss; }
    __syncthreads();
    if (threadIdx.x == 0) {
        float ts  = red[0] + red[1] + red[2] + red[3];
        float tss = red[4] + red[5] + red[6] + red[7];
        float mu  = ts * (1.0f / DIM_);
        float var = tss * (1.0f / DIM_) - mu * mu;
        red[8] = mu;
        red[9] = rsqrtf(var + 1e-5f);
    }
    __syncthreads();
    float mu = red[8], rs = red[9];
    float4 gg = ((const float4*)g)[threadIdx.x];
    float4 bb = ((const float4*)b)[threadIdx.x];
    u16x4 o;
    o[0] = f2bf((v.x - mu) * rs * gg.x + bb.x);
    o[1] = f2bf((v.y - mu) * rs * gg.y + bb.y);
    o[2] = f2bf((v.z - mu) * rs * gg.z + bb.z);
    o[3] = f2bf((v.w - mu) * rs * gg.w + bb.w);
    ((u16x4*)(y + (size_t)row * DIM_))[threadIdx.x] = o;
}

// ---------------------------------------------------------------------------
// fp32 -> bf16 cast (context), float4 per thread
// ---------------------------------------------------------------------------
__global__ __launch_bounds__(256) void cast_kernel(const float* __restrict__ in,
                                                   u16* __restrict__ out) {
    int i = blockIdx.x * 256 + threadIdx.x;
    float4 v = ((const float4*)in)[i];
    u16x4 o = {f2bf(v.x), f2bf(v.y), f2bf(v.z), f2bf(v.w)};
    ((u16x4*)out)[i] = o;
}

// ---------------------------------------------------------------------------
// Weight transpose + cast: W[K][N] fp32 -> Wt[N][K] bf16. 32x32 tiles.
// ---------------------------------------------------------------------------
__global__ __launch_bounds__(256) void transpose_cast(
    const float* __restrict__ W, u16* __restrict__ Wt, int Kdim, int Ndim) {
    __shared__ float tile[32][33];
    int bx = blockIdx.x * 32;  // n
    int by = blockIdx.y * 32;  // k
    int t = threadIdx.x;
    int kl = t >> 3, n4 = (t & 7) * 4;
    float4 v = *(const float4*)(W + (size_t)(by + kl) * Ndim + bx + n4);
    tile[kl][n4 + 0] = v.x; tile[kl][n4 + 1] = v.y;
    tile[kl][n4 + 2] = v.z; tile[kl][n4 + 3] = v.w;
    __syncthreads();
    int nl = t >> 3, k4 = (t & 7) * 4;
    u16x4 o;
    #pragma unroll
    for (int j = 0; j < 4; ++j) o[j] = f2bf(tile[k4 + j][nl]);
    *(u16x4*)(Wt + (size_t)(bx + nl) * Kdim + by + k4) = o;
}

// ---------------------------------------------------------------------------
// MFMA GEMM, depth-2 prefetch pipeline + XCD-aware 1D grid swizzle (T1).
// Launched on a FLAT grid of nwg = nx*ny*SPLITK blocks (nwg % 8 == 0);
// work id w = (bid&7)*(nwg/8) + bid>>3  ->  XCD k owns contiguous w-chunk,
// so blocks sharing an A-panel (consecutive x at same y) hit the same L2.
// C[M,N] = A[M,K] * Bt[N,K]^T, bf16 in, fp32 acc. 128x128 tile, BK=32,
// 4 waves (2x2), 16 mfma/K-step. SPLITK>1: partials via fp32 atomicAdd.
// EPI: 0 = bf16 out; 1 = +bias+gelu bf16; 2 = fp32 residual += acc+bias;
//      4 = bf16 out + V-part (col>=2048) -> vt (QKV gemm, rpb=1024)
//      5 = bf16 out + V-part (col>=1024) -> vt (KV  gemm, rpb=2048)
// ---------------------------------------------------------------------------
template <int EPI, int SPLITK>
__global__ __launch_bounds__(256) void gemm_mfma(
    const u16* __restrict__ A, const u16* __restrict__ Bt,
    const float* __restrict__ bias, void* __restrict__ Cout,
    u16* __restrict__ vt, int Mdim, int Ndim, int Kdim, int nx, int ny) {
    __shared__ __align__(16) u16 As[4][128 * 32];
    __shared__ __align__(16) u16 Bs[4][128 * 32];
    const int t = threadIdx.x;
    const int lane = t & 63, w = t >> 6;
    const int c = lane & 15, g = lane >> 4;
    const int wy = w >> 1, wx = w & 1;

    // T1 bijective XCD swizzle (nwg % 8 == 0)
    const int nwg = gridDim.x;
    const int wid = (blockIdx.x & 7) * (nwg >> 3) + (blockIdx.x >> 3);
    const int bx = wid % nx;
    const int by = (wid / nx) % ny;
    const int bz = wid / (nx * ny);
    const int m0 = by * 128, n0 = bx * 128;

    f32x4 acc[4][4] = {};

    const int srow = w * 32 + (lane >> 2);
    const int scb  = (((lane & 3) ^ ((srow >> 1) & 3)) * 8);
    const u16* Ag = A + (size_t)(m0 + srow) * Kdim + scb;
    const u16* Bg = Bt + (size_t)(n0 + srow) * Kdim + scb;

    auto stage = [&](int buf, int k0) {
        GLOAD16(Ag + k0, &As[buf][w * 1024]);
        GLOAD16(Ag + k0 + (size_t)16 * Kdim, &As[buf][w * 1024 + 512]);
        GLOAD16(Bg + k0, &Bs[buf][w * 1024]);
        GLOAD16(Bg + k0 + (size_t)16 * Kdim, &Bs[buf][w * 1024 + 512]);
    };
    const int rsw = (c >> 1) & 3;
    auto compute = [&](int buf) {
        bf16x8 a[4], b[4];
        #pragma unroll
        for (int i = 0; i < 4; ++i)
            a[i] = *(const bf16x8*)&As[buf][(wy * 64 + i * 16 + c) * 32 +
                                            ((g ^ rsw) * 8)];
        #pragma unroll
        for (int i = 0; i < 4; ++i)
            b[i] = *(const bf16x8*)&Bs[buf][(wx * 64 + i * 16 + c) * 32 +
                                            ((g ^ rsw) * 8)];
        __builtin_amdgcn_s_setprio(1);
        #pragma unroll
        for (int i = 0; i < 4; ++i)
            #pragma unroll
            for (int j = 0; j < 4; ++j)
                acc[i][j] = __builtin_amdgcn_mfma_f32_16x16x32_bf16(
                    a[i], b[j], acc[i][j], 0, 0, 0);
        __builtin_amdgcn_s_setprio(0);
    };

    const int kchunk = Kdim / SPLITK;
    const int kbeg = bz * kchunk;
    const int nsteps = kchunk / 32;

    stage(0, kbeg);
    stage(1, kbeg + 32);
    int s = 0;
    for (; s + 2 < nsteps; ++s) {
        stage((s + 2) & 3, kbeg + (s + 2) * 32);
        asm volatile("s_waitcnt vmcnt(8)" ::: "memory");
        __builtin_amdgcn_s_barrier();
        compute(s & 3);
    }
    asm volatile("s_waitcnt vmcnt(4)" ::: "memory");
    __builtin_amdgcn_s_barrier();
    compute(s & 3);
    ++s;
    asm volatile("s_waitcnt vmcnt(0)" ::: "memory");
    __builtin_amdgcn_s_barrier();
    compute(s & 3);

    constexpr int VTHRESH = (EPI == 4) ? 2048 : 1024;
    constexpr int RPB     = (EPI == 4) ? 1024 : 2048;
    constexpr int KVL     = (EPI == 4) ? 1024 : 2048;

    #pragma unroll
    for (int i = 0; i < 4; ++i) {
        int row0 = m0 + wy * 64 + i * 16 + g * 4;
        #pragma unroll
        for (int j = 0; j < 4; ++j) {
            int col = n0 + wx * 64 + j * 16 + c;
            u16x4 o4;
            #pragma unroll
            for (int r = 0; r < 4; ++r) {
                float v = acc[i][j][r];
                size_t idx = (size_t)(row0 + r) * Ndim + col;
                if constexpr (EPI == 0 || EPI == 4 || EPI == 5) {
                    u16 bv = f2bf(v);
                    ((u16*)Cout)[idx] = bv;
                    o4[r] = bv;
                } else if constexpr (EPI == 1) {
                    v += bias[col];
                    v = 0.5f * v * (1.0f + erff(v * 0.70710678118654752f));
                    ((u16*)Cout)[idx] = f2bf(v);
                } else {
                    float* Cf = (float*)Cout;
                    float add = v + ((SPLITK == 1 || bz == 0) ? bias[col] : 0.f);
                    if constexpr (SPLITK > 1)
                        atomicAdd(&Cf[idx], add);
                    else
                        Cf[idx] += add;
                }
            }
            if constexpr (EPI == 4 || EPI == 5) {
                if (n0 + wx * 64 + j * 16 >= VTHRESH) {
                    int hh = (col - VTHRESH) >> 6;
                    int dd = col & 63;
                    int bi = row0 / RPB;
                    int kv = row0 % RPB;
                    *(u16x4*)&vt[(((size_t)bi * HEADS_ + hh) * 64 + dd) * KVL +
                                 kv] = o4;
                }
            }
        }
    }
}

// ---------------------------------------------------------------------------
// MFMA flash attention, XCD-swizzled 1D grid (1024 blocks: x=qblk,h,b with
// the 16 qblk blocks sharing a (b,h) K/V panel mapped to one XCD).
// Block = 4 waves, 64 q-rows (16/wave), one (b,h). KVBLK=64, double-buffered.
// Swapped QK^T (mfma(K,Q)); in-register softmax; P redistributed via shfl.
// SA mask applied only when the 64-key tile has any masked key (ballot).
// ---------------------------------------------------------------------------
template <int KLEN, int IS_SA>
__global__ __launch_bounds__(256) void attn_mfma2(
    const u16* __restrict__ Qsrc, const u16* __restrict__ Ksrc,
    const u16* __restrict__ Vtg, const int* __restrict__ mask,
    u16* __restrict__ O) {
    constexpr int QSTR = IS_SA ? 3 * INNER_ : INNER_;
    constexpr int KSTR = IS_SA ? 3 * INNER_ : 2 * INNER_;
    constexpr int KOFF = IS_SA ? INNER_ : 0;

    __shared__ __align__(16) u16 Ks[2][64 * 64];
    __shared__ __align__(16) u16 Vs[2][64 * 64];

    const int t = threadIdx.x;
    const int lane = t & 63, w = t >> 6;
    const int c = lane & 15, g = lane >> 4;

    const int nwg = gridDim.x;  // 1024
    const int wid = (blockIdx.x & 7) * (nwg >> 3) + (blockIdx.x >> 3);
    const int qb = wid & 15;
    const int h  = (wid >> 4) & 15;
    const int bb = wid >> 8;
    const int q0 = qb * 64;
    const int kvbase = bb * KLEN;

    const u16* qp =
        Qsrc + (size_t)(bb * N_ + q0 + w * 16 + c) * QSTR + h * 64 + g * 8;
    bf16x8 qf[2];
    qf[0] = *(const bf16x8*)qp;
    qf[1] = *(const bf16x8*)(qp + 32);

    const int sl_r = lane >> 3;
    const int scol = ((lane & 7) ^ sl_r) * 8;  // swizzled source col (u16)
    const int r0 = w * 16, r1 = w * 16 + 8;
    const u16* Kg0 = Ksrc + (size_t)(kvbase + r0 + sl_r) * KSTR + KOFF +
                     h * 64 + scol;
    const u16* Kg1 = Ksrc + (size_t)(kvbase + r1 + sl_r) * KSTR + KOFF +
                     h * 64 + scol;
    const u16* Vg0 =
        Vtg + ((size_t)(bb * HEADS_ + h) * 64 + r0 + sl_r) * KLEN + scol;
    const u16* Vg1 =
        Vtg + ((size_t)(bb * HEADS_ + h) * 64 + r1 + sl_r) * KLEN + scol;

    auto stageKV = [&](int buf, int kt) {
        GLOAD16(Kg0 + (size_t)kt * 64 * KSTR, &Ks[buf][r0 * 64]);
        GLOAD16(Kg1 + (size_t)kt * 64 * KSTR, &Ks[buf][r1 * 64]);
        GLOAD16(Vg0 + kt * 64, &Vs[buf][r0 * 64]);
        GLOAD16(Vg1 + kt * 64, &Vs[buf][r1 * 64]);
    };

    f32x4 o[4] = {};
    float mr = -1e30f, lr = 0.f;
    const int srcA = c + 32 * (g & 1);
    const int srcB = srcA + 16;
    const bool hi = (g & 2) != 0;
    constexpr int NT = KLEN / 64;

    stageKV(0, 0);
    __syncthreads();
    int cur = 0;

    for (int kt = 0; kt < NT; ++kt) {
        if (kt + 1 < NT) stageKV(cur ^ 1, kt + 1);

        // S^T = K Q^T : sv[kvb] holds S[q = c][kv = kvb*16 + g*4 + r]
        f32x4 sv[4] = {};
        #pragma unroll
        for (int kvb = 0; kvb < 4; ++kvb) {
            #pragma unroll
            for (int f = 0; f < 2; ++f) {
                bf16x8 kf = *(const bf16x8*)&Ks[cur][(kvb * 16 + c) * 64 +
                                                     (((g + 4 * f) ^ (c & 7)) * 8)];
                sv[kvb] = __builtin_amdgcn_mfma_f32_16x16x32_bf16(
                    kf, qf[f], sv[kvb], 0, 0, 0);
            }
        }
        #pragma unroll
        for (int kvb = 0; kvb < 4; ++kvb)
            #pragma unroll
            for (int r = 0; r < 4; ++r) sv[kvb][r] *= 0.125f;

        if constexpr (IS_SA) {
            int mbit = mask[bb * N_ + kt * 64 + lane];
            unsigned long long ball = __ballot(mbit != 0);
            if (ball != ~0ull) {  // some key masked: apply -1e11 bias
                float negm_reg = 1e11f * (float)(1 - mbit);
                #pragma unroll
                for (int kvb = 0; kvb < 4; ++kvb)
                    #pragma unroll
                    for (int r = 0; r < 4; ++r)
                        sv[kvb][r] -= __shfl(negm_reg, kvb * 16 + g * 4 + r);
            }
        }

        float tm = sv[0][0];
        #pragma unroll
        for (int kvb = 0; kvb < 4; ++kvb)
            #pragma unroll
            for (int r = 0; r < 4; ++r) tm = fmaxf(tm, sv[kvb][r]);
        tm = fmaxf(tm, __shfl_xor(tm, 16));
        tm = fmaxf(tm, __shfl_xor(tm, 32));
        float mnew = fmaxf(mr, tm);
        float corr = __expf(mr - mnew);
        mr = mnew;

        float ps = 0.f;
        #pragma unroll
        for (int kvb = 0; kvb < 4; ++kvb)
            #pragma unroll
            for (int r = 0; r < 4; ++r) {
                float p = __expf(sv[kvb][r] - mr);
                sv[kvb][r] = p;
                ps += p;
            }
        ps += __shfl_xor(ps, 16);
        ps += __shfl_xor(ps, 32);
        lr = lr * corr + ps;

        float corrO[4];
        #pragma unroll
        for (int r = 0; r < 4; ++r) corrO[r] = __shfl(corr, g * 4 + r);
        #pragma unroll
        for (int db = 0; db < 4; ++db)
            #pragma unroll
            for (int r = 0; r < 4; ++r) o[db][r] *= corrO[r];

        unsigned pk[4][2];
        #pragma unroll
        for (int kvb = 0; kvb < 4; ++kvb)
            #pragma unroll
            for (int j = 0; j < 2; ++j)
                pk[kvb][j] = ((unsigned)f2bf(sv[kvb][2 * j + 1]) << 16) |
                             (unsigned)f2bf(sv[kvb][2 * j]);

        #pragma unroll
        for (int pv = 0; pv < 2; ++pv) {
            int a0 = __shfl((int)pk[2 * pv][0], srcA);
            int b0 = __shfl((int)pk[2 * pv + 1][0], srcA);
            int a1 = __shfl((int)pk[2 * pv][1], srcA);
            int b1 = __shfl((int)pk[2 * pv + 1][1], srcA);
            int a2 = __shfl((int)pk[2 * pv][0], srcB);
            int b2 = __shfl((int)pk[2 * pv + 1][0], srcB);
            int a3 = __shfl((int)pk[2 * pv][1], srcB);
            int b3 = __shfl((int)pk[2 * pv + 1][1], srcB);
            i32x4 tw = {hi ? b0 : a0, hi ? b1 : a1, hi ? b2 : a2,
                        hi ? b3 : a3};
            bf16x8 pa = *(bf16x8*)&tw;
            #pragma unroll
            for (int db = 0; db < 4; ++db) {
                bf16x8 vf = *(const bf16x8*)&Vs[cur][(db * 16 + c) * 64 +
                                                     (((g + 4 * pv) ^ (c & 7)) * 8)];
                o[db] = __builtin_amdgcn_mfma_f32_16x16x32_bf16(pa, vf, o[db],
                                                                0, 0, 0);
            }
        }
        __syncthreads();
        cur ^= 1;
    }

    float inv = 1.f / lr;
    float invO[4];
    #pragma unroll
    for (int r = 0; r < 4; ++r) invO[r] = __shfl(inv, g * 4 + r);
    #pragma unroll
    for (int db = 0; db < 4; ++db)
        #pragma unroll
        for (int r = 0; r < 4; ++r) {
            size_t idx =
                (size_t)(bb * N_ + q0 + w * 16 + g * 4 + r) * INNER_ +
                h * 64 + db * 16 + c;
            O[idx] = f2bf(o[db][r] * invO[r]);
        }
}

// ---------------------------------------------------------------------------
extern "C" void kernel_launch(void* const* d_in, const int* in_sizes, int n_in,
                              void* d_out, int out_size, void* d_ws,
                              size_t ws_size, hipStream_t stream) {
    const float* x     = (const float*)d_in[0];
    const float* ctx   = (const float*)d_in[1];
    const int*   mask  = (const int*)d_in[2];
    const float* ln_g  = (const float*)d_in[3];
    const float* ln_b  = (const float*)d_in[4];
    const float* Wqkv  = (const float*)d_in[5];
    const float* Wo_sa = (const float*)d_in[6];
    const float* bo_sa = (const float*)d_in[7];
    const float* Wkv   = (const float*)d_in[8];
    const float* Wq    = (const float*)d_in[9];
    const float* Wo_ca = (const float*)d_in[10];
    const float* bo_ca = (const float*)d_in[11];
    const float* W1    = (const float*)d_in[12];
    const float* b1    = (const float*)d_in[13];
    const float* W2    = (const float*)d_in[14];
    const float* b2    = (const float*)d_in[15];
    float* xout = (float*)d_out;

    char* ws = (char*)d_ws;
    u16* lnout = (u16*)ws;                        // 8MB (also attn out)
    u16* big   = (u16*)(ws + (8ull << 20));       // 32MB: qkv / kv / h1
    u16* qca   = (u16*)(ws + (40ull << 20));      // 8MB
    u16* ctxb  = (u16*)(ws + (48ull << 20));      // 16MB
    u16* wt    = (u16*)(ws + (64ull << 20));      // 8MB: transposed weight
    u16* vt_sa = (u16*)(ws + (72ull << 20));      // 8MB: V^T self-attn
    u16* vt_ca = (u16*)(ws + (80ull << 20));      // 16MB: V^T cross-attn
    u16* aout  = lnout;

    hipMemcpyAsync(xout, x, sizeof(float) * B_ * N_ * DIM_,
                   hipMemcpyDeviceToDevice, stream);
    cast_kernel<<<B_ * M_ * CTX_ / 1024, 256, 0, stream>>>(ctx, ctxb);

    const int ROWS = B_ * N_;    // 4096
    const int CROWS = B_ * M_;   // 8192
    dim3 blk(256);

    for (int i = 0; i < DEPTH_; ++i) {
        const float* g  = ln_g + (size_t)(i * 3) * DIM_;
        const float* bb = ln_b + (size_t)(i * 3) * DIM_;

        // ---- self-attention ----
        ln_kernel<<<ROWS, blk, 0, stream>>>(xout, g, bb, lnout);
        transpose_cast<<<dim3(3 * INNER_ / 32, DIM_ / 32), blk, 0, stream>>>(
            Wqkv + (size_t)i * DIM_ * 3 * INNER_, wt, DIM_, 3 * INNER_);
        gemm_mfma<4, 1><<<24 * 32, blk, 0, stream>>>(
            lnout, wt, nullptr, big, vt_sa, ROWS, 3 * INNER_, DIM_, 24, 32);
        attn_mfma2<N_, 1><<<1024, blk, 0, stream>>>(big, big, vt_sa, mask,
                                                    aout);
        transpose_cast<<<dim3(DIM_ / 32, INNER_ / 32), blk, 0, stream>>>(
            Wo_sa + (size_t)i * INNER_ * DIM_, wt, INNER_, DIM_);
        gemm_mfma<2, 2><<<8 * 32 * 2, blk, 0, stream>>>(
            aout, wt, bo_sa + (size_t)i * DIM_, xout, nullptr, ROWS, DIM_,
            INNER_, 8, 32);

        // ---- cross-attention ----
        ln_kernel<<<ROWS, blk, 0, stream>>>(xout, g + DIM_, bb + DIM_, lnout);
        transpose_cast<<<dim3(INNER_ / 32, DIM_ / 32), blk, 0, stream>>>(
            Wq + (size_t)i * DIM_ * INNER_, wt, DIM_, INNER_);
        gemm_mfma<0, 1><<<8 * 32, blk, 0, stream>>>(
            lnout, wt, nullptr, qca, nullptr, ROWS, INNER_, DIM_, 8, 32);
        transpose_cast<<<dim3(2 * INNER_ / 32, CTX_ / 32), blk, 0, stream>>>(
            Wkv + (size_t)i * CTX_ * 2 * INNER_, wt, CTX_, 2 * INNER_);
        gemm_mfma<5, 1><<<16 * 64, blk, 0, stream>>>(
            ctxb, wt, nullptr, big, vt_ca, CROWS, 2 * INNER_, CTX_, 16, 64);
        attn_mfma2<M_, 0><<<1024, blk, 0, stream>>>(qca, big, vt_ca, mask,
                                                    aout);
        transpose_cast<<<dim3(DIM_ / 32, INNER_ / 32), blk, 0, stream>>>(
            Wo_ca + (size_t)i * INNER_ * DIM_, wt, INNER_, DIM_);
        gemm_mfma<2, 2><<<8 * 32 * 2, blk, 0, stream>>>(
            aout, wt, bo_ca + (size_t)i * DIM_, xout, nullptr, ROWS, DIM_,
            INNER_, 8, 32);

        // ---- feed-forward ----
        ln_kernel<<<ROWS, blk, 0, stream>>>(xout, g + 2 * DIM_, bb + 2 * DIM_,
                                            lnout);
        transpose_cast<<<dim3(MLP_ / 32, DIM_ / 32), blk, 0, stream>>>(
            W1 + (size_t)i * DIM_ * MLP_, wt, DIM_, MLP_);
        gemm_mfma<1, 1><<<32 * 32, blk, 0, stream>>>(
            lnout, wt, b1 + (size_t)i * MLP_, big, nullptr, ROWS, MLP_, DIM_,
            32, 32);
        transpose_cast<<<dim3(DIM_ / 32, MLP_ / 32), blk, 0, stream>>>(
            W2 + (size_t)i * MLP_ * DIM_, wt, MLP_, DIM_);
        gemm_mfma<2, 2><<<8 * 32 * 2, blk, 0, stream>>>(
            big, wt, b2 + (size_t)i * DIM_, xout, nullptr, ROWS, DIM_, MLP_,
            8, 32);
    }
}